// Round 1
// baseline (356.123 us; speedup 1.0000x reference)
//
#include <hip/hip_runtime.h>

// one_hot @ weight where one_hot rows are exact {0,1} one-hot rows.
// Dense GEMM == row gather, bit-exact in fp32. We scan each one_hot row to
// find the hot index (with chunked early exit to skip ~44% of the 256 MB
// one_hot read on average), then copy weight[idx] to out[n].

constexpr int N_TOKENS = 8192;
constexpr int VOCAB    = 8192;
constexpr int D        = 1024;
constexpr int BLOCK    = 256;
constexpr int CHUNKS   = VOCAB / (BLOCK * 4);   // 8 chunks of 1024 floats

__global__ __launch_bounds__(BLOCK) void onehot_gather_kernel(
    const float* __restrict__ one_hot,
    const float* __restrict__ weight,
    float* __restrict__ out) {
    const int n = blockIdx.x;
    const int t = threadIdx.x;

    __shared__ int s_idx;
    if (t == 0) s_idx = -1;
    __syncthreads();

    const float4* row = (const float4*)(one_hot + (size_t)n * VOCAB);

    int idx = -1;
    for (int it = 0; it < CHUNKS; ++it) {
        const int pos = it * BLOCK + t;          // float4 index within row
        const float4 v = row[pos];
        if (v.x != 0.f || v.y != 0.f || v.z != 0.f || v.w != 0.f) {
            const int off = (v.x != 0.f) ? 0 : (v.y != 0.f) ? 1
                          : (v.z != 0.f) ? 2 : 3;
            s_idx = pos * 4 + off;               // exactly one lane writes
        }
        __syncthreads();                         // make write visible
        idx = s_idx;                             // uniform read
        __syncthreads();                         // protect read from next iter's write
        if (idx >= 0) break;                     // uniform break (no divergent barrier)
    }

    // Copy weight[idx] -> out[n]: 1024 floats = 256 lanes x float4.
    float4* orow = (float4*)(out + (size_t)n * D);
    if (idx >= 0) {
        const float4* wrow = (const float4*)(weight + (size_t)idx * D);
        orow[t] = wrow[t];
    } else {
        // all-zero one_hot row -> GEMM gives zeros
        orow[t] = make_float4(0.f, 0.f, 0.f, 0.f);
    }
}

extern "C" void kernel_launch(void* const* d_in, const int* in_sizes, int n_in,
                              void* d_out, int out_size, void* d_ws, size_t ws_size,
                              hipStream_t stream) {
    const float* one_hot = (const float*)d_in[0];   // [N_TOKENS, VOCAB] f32
    const float* weight  = (const float*)d_in[1];   // [VOCAB, D] f32
    float* out           = (float*)d_out;           // [N_TOKENS, D] f32

    onehot_gather_kernel<<<dim3(N_TOKENS), dim3(BLOCK), 0, stream>>>(
        one_hot, weight, out);
}